// Round 6
// baseline (199.580 us; speedup 1.0000x reference)
//
#include <hip/hip_runtime.h>
#include <math.h>

// Problem constants
#define NB   16
#define NC   64
#define HWs  4096
#define NPS  1024
#define LOG2E 1.44269504088896341f

// ws layout in ushort (bf16 bit patterns)
static constexpr size_t PHI_OFF = (size_t)NB * HWs * 8;            // theta: [b][4096][8]
static constexpr size_t GT_OFF  = PHI_OFF + (size_t)NB * NPS * 8;  // phi:   [b][1024][8]
// gT: [b][32][1024]; total 1,179,648 ushorts = 2.25 MB

typedef short s16x8 __attribute__((ext_vector_type(8)));
typedef float f32x4 __attribute__((ext_vector_type(4)));

#define LD8G(p) (*(const s16x8*)(p))

__device__ inline unsigned short f2bf(float f) {
    unsigned int u = __float_as_uint(f);
    u += 0x7fffu + ((u >> 16) & 1u);          // RNE
    return (unsigned short)(u >> 16);
}
__device__ inline unsigned int pk2(float a, float b) {
    unsigned int ua = __float_as_uint(a); ua += 0x7fffu + ((ua >> 16) & 1u);
    unsigned int ub = __float_as_uint(b); ub += 0x7fffu + ((ub >> 16) & 1u);
    return (ua >> 16) | (ub & 0xffff0000u);
}

// ---------------------------------------------------------------------------
// Kernel 1 (v4): register-tiled projection GEMM. 256 blocks x 256 threads.
// Block = (b, rowgroup rg of 4 image rows = 256 px). x staged to LDS in
// pool-quad-major layout xs[ci][quad*4 + (dy*2+dx)]; weights staged to LDS.
// Wave = output-quarter outq (12 rows of [theta(8);phi(8);g(32)]); lane =
// 2x2 pool quad. Per 4-ci group: 12 broadcast b128 W-reads + 4 b128 x-reads
// -> 192 FMAs (VALU-bound, no scalar-load gamble). Pooling: 3 in-thread max.
// ---------------------------------------------------------------------------
__global__ __launch_bounds__(256) void k_proj(
    const float* __restrict__ x, const float* __restrict__ Wt,
    const float* __restrict__ Wp, const float* __restrict__ Wg,
    unsigned short* __restrict__ ws)
{
    __shared__ __align__(16) float xs[64 * 256];   // 64 KB, [ci][quad*4+sub]
    __shared__ __align__(16) float wlds[48 * 64];  // 12 KB: rows 0-7 Wt, 8-15 Wp, 16-47 Wg

    unsigned short* theta = ws;
    unsigned short* phi   = ws + PHI_OFF;
    unsigned short* gT    = ws + GT_OFF;

    const int tid = threadIdx.x;
    const int blk = blockIdx.x;
    const int b   = blk >> 4;
    const int rg  = blk & 15;                  // image rows 4rg..4rg+3

    // ---- stage weights ----
    {
        float4* wl4 = (float4*)wlds;
        if (tid < 128) wl4[tid] = ((const float4*)Wt)[tid];
        else           wl4[tid] = ((const float4*)Wp)[tid - 128];
        wl4[256 + tid] = ((const float4*)Wg)[tid];
        wl4[512 + tid] = ((const float4*)Wg)[256 + tid];
    }
    // ---- stage x: slice x[b][ci][4rg*64 .. +256) -> pool-quad-major ----
    const float* xsrc = x + (size_t)b * NC * HWs + rg * 256;
#pragma unroll
    for (int i = 0; i < 16; ++i) {
        const int f  = i * 256 + tid;          // f4 index, 0..4095
        const int ci = f >> 6;
        const int c4 = f & 63;
        float4 v = *(const float4*)(xsrc + (size_t)ci * HWs + c4 * 4);
        const int e0 = 4 * c4;                 // linear px-in-slice of v.x
        const int r  = e0 >> 6;                // row within group (0..3)
        const int c0 = e0 & 63;
        const int qm = r >> 1, dy = r & 1;
        const int q0i = qm * 32 + (c0 >> 1);   // quad of (v.x,v.y)
        float* base = xs + ci * 256;
        *(float2*)(base + q0i * 4 + dy * 2)       = make_float2(v.x, v.y);
        *(float2*)(base + (q0i + 1) * 4 + dy * 2) = make_float2(v.z, v.w);
    }
    __syncthreads();

    const int outq = __builtin_amdgcn_readfirstlane(tid >> 6);  // 0..3
    const int lane = tid & 63;
    const int qm   = lane >> 5;                // quad row-pair (0/1)
    const int qc   = lane & 31;                // quad col

    f32x4 acc[12];
#pragma unroll
    for (int j = 0; j < 12; ++j)
#pragma unroll
        for (int p = 0; p < 4; ++p) acc[j][p] = 0.f;

    const float* wbase = wlds + outq * 12 * 64;
    for (int cg = 0; cg < 16; ++cg) {          // 4-ci groups
        float4 xv[4];
#pragma unroll
        for (int u = 0; u < 4; ++u)
            xv[u] = *(const float4*)(xs + (cg * 4 + u) * 256 + lane * 4);
#pragma unroll
        for (int j = 0; j < 12; ++j) {
            float4 w4 = *(const float4*)(wbase + j * 64 + cg * 4);  // broadcast
            acc[j][0] += w4.x * xv[0].x + w4.y * xv[1].x + w4.z * xv[2].x + w4.w * xv[3].x;
            acc[j][1] += w4.x * xv[0].y + w4.y * xv[1].y + w4.z * xv[2].y + w4.w * xv[3].y;
            acc[j][2] += w4.x * xv[0].z + w4.y * xv[1].z + w4.z * xv[2].z + w4.w * xv[3].z;
            acc[j][3] += w4.x * xv[0].w + w4.y * xv[1].w + w4.z * xv[2].w + w4.w * xv[3].w;
        }
    }

    const int px00 = (4 * rg + 2 * qm) * 64 + 2 * qc;       // quad origin px
    const int ps   = (2 * rg + qm) * 32 + qc;               // pooled index

    if (outq == 0) {
        // theta rows 0..7 (j=0..7), all 4 px, *log2e, packed b128 stores
        const int pxo[4] = {px00, px00 + 1, px00 + 64, px00 + 65};
#pragma unroll
        for (int p = 0; p < 4; ++p) {
            uint4 pkd;
            pkd.x = pk2(acc[0][p] * LOG2E, acc[1][p] * LOG2E);
            pkd.y = pk2(acc[2][p] * LOG2E, acc[3][p] * LOG2E);
            pkd.z = pk2(acc[4][p] * LOG2E, acc[5][p] * LOG2E);
            pkd.w = pk2(acc[6][p] * LOG2E, acc[7][p] * LOG2E);
            *(uint4*)(theta + ((size_t)b * HWs + pxo[p]) * 8) = pkd;
        }
    }
    // pooled outputs: out row oo = outq*12 + j; phi for 8<=oo<16, g for oo>=16
#pragma unroll
    for (int j = 0; j < 12; ++j) {
        const int oo = outq * 12 + j;
        if (oo < 8) continue;                  // theta handled above
        const float pm = fmaxf(fmaxf(acc[j][0], acc[j][1]), fmaxf(acc[j][2], acc[j][3]));
        if (oo < 16) phi[((size_t)b * NPS + ps) * 8 + (oo - 8)] = f2bf(pm);
        else         gT[((size_t)b * 32 + (oo - 16)) * NPS + ps] = f2bf(pm);
    }
}

// ---------------------------------------------------------------------------
// Kernel 2 (v4): MFMA attention, s-split across wave pairs.
// 2048 blocks; block = (b, 32-q tile); wave = (qh, sh): 16 q, 8 key-tiles
// (s-half sh). No online softmax (|S*log2e| < ~6). Lagged PV with
// double-buffered P per wave; phB persistent-zero (exec-masked loads);
// pointer-increment addressing; fully unrolled. Partials combined by
// O/l ADDITION across sh (legal: plain exp2, no max state).
// ---------------------------------------------------------------------------
__global__ __launch_bounds__(256, 6) void k_attn(
    const float* __restrict__ x, const float* __restrict__ Wo,
    const float* __restrict__ gamma_p, const unsigned short* __restrict__ ws,
    float* __restrict__ out)
{
    __shared__ __align__(16) unsigned char smem[18432];
    // P: wave*4608B (2 bufs x 16q x 72s x 2B). After sync: otile f32[32][36]
    // at byte 0 (4608B); combine area at byte 8192 (2 x 64 x 12 f32 = 6144B).

    const int tid  = threadIdx.x;
    const int wave = __builtin_amdgcn_readfirstlane(tid >> 6);
    const int lane = tid & 63;
    const int quad = lane >> 4, lr = lane & 15;
    const int blk  = blockIdx.x;
    const int b    = blk >> 7;
    const int q0   = (blk & 127) * 32;
    const int qh   = wave >> 1;                // q-half (0/1)
    const int sh   = wave & 1;                 // s-half (0/1)
    const int qw0  = q0 + qh * 16;

    const unsigned short* th = ws + (size_t)b * HWs * 8;
    const unsigned short* ph = ws + PHI_OFF + (size_t)b * NPS * 8;
    const unsigned short* gp = ws + GT_OFF + (size_t)b * 32 * NPS;
    unsigned short* Pw = (unsigned short*)smem + wave * 2304;   // 2 x 1152 ushorts

    const s16x8 zf = {0, 0, 0, 0, 0, 0, 0, 0};

    s16x8 thA = zf;
    if (quad == 0) thA = LD8G(th + (size_t)(qw0 + lr) * 8);

    f32x4 O[2];
    f32x4 l4;
#pragma unroll
    for (int r = 0; r < 4; ++r) { O[0][r] = 0.f; O[1][r] = 0.f; l4[r] = 0.f; }

    s16x8 phB[4] = {zf, zf, zf, zf};           // quads 1-3 stay zero forever

    const unsigned short* php = ph + (size_t)(sh * 512 + lr) * 8;
    const unsigned short* gb0 = gp + (size_t)lr * NPS + sh * 512 + quad * 8;
    const unsigned short* gb1 = gb0 + 16 * NPS;
    const f32x4 zc = {0.f, 0.f, 0.f, 0.f};

#pragma unroll
    for (int i = 0; i < 8; ++i) {
        // phi B-frags for tile i (exec-masked: only quad 0 carries data)
        if (quad == 0) {
            phB[0] = LD8G(php + 0);
            phB[1] = LD8G(php + 128);
            phB[2] = LD8G(php + 256);
            phB[3] = LD8G(php + 384);
        }
        php += 512;

        // lagged PV for tile i-1 (Gf + Pf loads issue early)
        if (i > 0) {
            s16x8 Gf0a = LD8G(gb0), Gf0b = LD8G(gb0 + 32);
            s16x8 Gf1a = LD8G(gb1), Gf1b = LD8G(gb1 + 32);
            const unsigned short* Pb = Pw + ((i - 1) & 1) * 1152 + lr * 72 + quad * 8;
            s16x8 Pf0 = *(const s16x8*)(Pb);
            s16x8 Pf1 = *(const s16x8*)(Pb + 32);
            O[0] = __builtin_amdgcn_mfma_f32_16x16x32_bf16(Pf0, Gf0a, O[0], 0, 0, 0);
            O[1] = __builtin_amdgcn_mfma_f32_16x16x32_bf16(Pf0, Gf1a, O[1], 0, 0, 0);
            O[0] = __builtin_amdgcn_mfma_f32_16x16x32_bf16(Pf1, Gf0b, O[0], 0, 0, 0);
            O[1] = __builtin_amdgcn_mfma_f32_16x16x32_bf16(Pf1, Gf1b, O[1], 0, 0, 0);
            gb0 += 64; gb1 += 64;
        }

        // scores tile i: D[q=quad*4+r][s=ss*16+lr]
        f32x4 S[4];
#pragma unroll
        for (int ss = 0; ss < 4; ++ss)
            S[ss] = __builtin_amdgcn_mfma_f32_16x16x32_bf16(thA, phB[ss], zc, 0, 0, 0);

        // p = exp2(S), accumulate l, store bf16 P to buf i&1
        unsigned short* Pbw = Pw + (i & 1) * 1152 + quad * 288 + lr;
#pragma unroll
        for (int ss = 0; ss < 4; ++ss)
#pragma unroll
            for (int r = 0; r < 4; ++r) {
                const float p = exp2f(S[ss][r]);
                l4[r] += p;
                Pbw[r * 72 + ss * 16] = (unsigned short)(__float_as_uint(p) >> 16);
            }
    }
    // drain: PV for tile 7 (buf 1; gb at tile-7 position)
    {
        s16x8 Gf0a = LD8G(gb0), Gf0b = LD8G(gb0 + 32);
        s16x8 Gf1a = LD8G(gb1), Gf1b = LD8G(gb1 + 32);
        const unsigned short* Pb = Pw + 1152 + lr * 72 + quad * 8;
        s16x8 Pf0 = *(const s16x8*)(Pb);
        s16x8 Pf1 = *(const s16x8*)(Pb + 32);
        O[0] = __builtin_amdgcn_mfma_f32_16x16x32_bf16(Pf0, Gf0a, O[0], 0, 0, 0);
        O[1] = __builtin_amdgcn_mfma_f32_16x16x32_bf16(Pf0, Gf1a, O[1], 0, 0, 0);
        O[0] = __builtin_amdgcn_mfma_f32_16x16x32_bf16(Pf1, Gf0b, O[0], 0, 0, 0);
        O[1] = __builtin_amdgcn_mfma_f32_16x16x32_bf16(Pf1, Gf1b, O[1], 0, 0, 0);
    }

    // ---- combine s-halves: sh1 publishes partials, sh0 adds ----
    float* comb = (float*)(smem + 8192);       // [qh][lane][12]
    __syncthreads();
    if (sh == 1) {
        float* c = comb + (size_t)(qh * 64 + lane) * 12;
        *(f32x4*)(c)     = O[0];
        *(f32x4*)(c + 4) = O[1];
        *(f32x4*)(c + 8) = l4;
    }
    __syncthreads();
    if (sh == 0) {
        const float* c = comb + (size_t)(qh * 64 + lane) * 12;
        f32x4 o0 = *(const f32x4*)(c);
        f32x4 o1 = *(const f32x4*)(c + 4);
        f32x4 lb = *(const f32x4*)(c + 8);
#pragma unroll
        for (int r = 0; r < 4; ++r) {
            O[0][r] += o0[r]; O[1][r] += o1[r]; l4[r] += lb[r];
        }
        // butterfly l over the 16-lane s-groups, then normalize
        f32x4 linv;
#pragma unroll
        for (int r = 0; r < 4; ++r) {
            float v = l4[r];
            v += __shfl_xor(v, 1);
            v += __shfl_xor(v, 2);
            v += __shfl_xor(v, 4);
            v += __shfl_xor(v, 8);
            linv[r] = 1.f / v;
        }
        float* otile = (float*)smem;           // [32 c][36 q-stride]
#pragma unroll
        for (int cs = 0; cs < 2; ++cs) {
            f32x4 v;
#pragma unroll
            for (int r = 0; r < 4; ++r) v[r] = O[cs][r] * linv[r];
            *(f32x4*)(otile + (cs * 16 + lr) * 36 + qh * 16 + quad * 4) = v;
        }
    }
    __syncthreads();

    // ---- Wo epilogue + residual: wave owns 16 oc rows; lane q = lane&31 ----
    const float* otile = (const float*)smem;
    const int qq = lane & 31;                  // upper half-wave duplicates
    float otcol[32];
#pragma unroll
    for (int c = 0; c < 32; ++c) otcol[c] = otile[c * 36 + qq];
    const float* wrow = Wo + wave * 16 * 32;   // scalar (wave uniform)
    const float gam = gamma_p[0];
#pragma unroll
    for (int j = 0; j < 16; ++j) {
        float acc = 0.f;
#pragma unroll
        for (int c = 0; c < 32; ++c) acc += wrow[j * 32 + c] * otcol[c];
        if (lane < 32) {
            const size_t a = ((size_t)b * NC + wave * 16 + j) * HWs + q0 + qq;
            out[a] = gam * acc + x[a];
        }
    }
}

extern "C" void kernel_launch(void* const* d_in, const int* in_sizes, int n_in,
                              void* d_out, int out_size, void* d_ws, size_t ws_size,
                              hipStream_t stream) {
    const float* x     = (const float*)d_in[0];
    const float* Wt    = (const float*)d_in[1];
    const float* Wp    = (const float*)d_in[2];
    const float* Wg    = (const float*)d_in[3];
    const float* Wo    = (const float*)d_in[4];
    const float* gamma = (const float*)d_in[5];
    float* out = (float*)d_out;
    unsigned short* ws = (unsigned short*)d_ws;

    k_proj<<<256, 256, 0, stream>>>(x, Wt, Wp, Wg, ws);
    k_attn<<<2048, 256, 0, stream>>>(x, Wo, gamma, ws, out);
}

// Round 7
// 142.021 us; speedup vs baseline: 1.4053x; 1.4053x over previous
//
#include <hip/hip_runtime.h>
#include <math.h>

// Problem constants
#define NB   16
#define NC   64
#define HWs  4096
#define NPS  1024
#define LOG2E 1.44269504088896341f

// ws layout in ushort (bf16 bit patterns)
static constexpr size_t PHI_OFF = (size_t)NB * HWs * 8;            // theta: [b][4096][8]
static constexpr size_t GT_OFF  = PHI_OFF + (size_t)NB * NPS * 8;  // phi:   [b][1024][8]
// gT: [b][32][1024]; total 1,179,648 ushorts = 2.25 MB

typedef short s16x8 __attribute__((ext_vector_type(8)));
typedef float f32x4 __attribute__((ext_vector_type(4)));

#define LD8G(p) (*(const s16x8*)(p))

__device__ inline unsigned short f2bf(float f) {
    unsigned int u = __float_as_uint(f);
    u += 0x7fffu + ((u >> 16) & 1u);          // RNE
    return (unsigned short)(u >> 16);
}
__device__ inline unsigned int pk2(float a, float b) {
    unsigned int ua = __float_as_uint(a); ua += 0x7fffu + ((ua >> 16) & 1u);
    unsigned int ub = __float_as_uint(b); ub += 0x7fffu + ((ub >> 16) & 1u);
    return (ua >> 16) | (ub & 0xffff0000u);
}

// ---------------------------------------------------------------------------
// Kernel 1 (v4, UNCHANGED from round 6 for clean attribution):
// register-tiled projection GEMM. 256 blocks x 256 threads.
// ---------------------------------------------------------------------------
__global__ __launch_bounds__(256) void k_proj(
    const float* __restrict__ x, const float* __restrict__ Wt,
    const float* __restrict__ Wp, const float* __restrict__ Wg,
    unsigned short* __restrict__ ws)
{
    __shared__ __align__(16) float xs[64 * 256];   // 64 KB, [ci][quad*4+sub]
    __shared__ __align__(16) float wlds[48 * 64];  // 12 KB: rows 0-7 Wt, 8-15 Wp, 16-47 Wg

    unsigned short* theta = ws;
    unsigned short* phi   = ws + PHI_OFF;
    unsigned short* gT    = ws + GT_OFF;

    const int tid = threadIdx.x;
    const int blk = blockIdx.x;
    const int b   = blk >> 4;
    const int rg  = blk & 15;                  // image rows 4rg..4rg+3

    // ---- stage weights ----
    {
        float4* wl4 = (float4*)wlds;
        if (tid < 128) wl4[tid] = ((const float4*)Wt)[tid];
        else           wl4[tid] = ((const float4*)Wp)[tid - 128];
        wl4[256 + tid] = ((const float4*)Wg)[tid];
        wl4[512 + tid] = ((const float4*)Wg)[256 + tid];
    }
    // ---- stage x: slice x[b][ci][4rg*64 .. +256) -> pool-quad-major ----
    const float* xsrc = x + (size_t)b * NC * HWs + rg * 256;
#pragma unroll
    for (int i = 0; i < 16; ++i) {
        const int f  = i * 256 + tid;          // f4 index, 0..4095
        const int ci = f >> 6;
        const int c4 = f & 63;
        float4 v = *(const float4*)(xsrc + (size_t)ci * HWs + c4 * 4);
        const int e0 = 4 * c4;                 // linear px-in-slice of v.x
        const int r  = e0 >> 6;                // row within group (0..3)
        const int c0 = e0 & 63;
        const int qm = r >> 1, dy = r & 1;
        const int q0i = qm * 32 + (c0 >> 1);   // quad of (v.x,v.y)
        float* base = xs + ci * 256;
        *(float2*)(base + q0i * 4 + dy * 2)       = make_float2(v.x, v.y);
        *(float2*)(base + (q0i + 1) * 4 + dy * 2) = make_float2(v.z, v.w);
    }
    __syncthreads();

    const int outq = __builtin_amdgcn_readfirstlane(tid >> 6);  // 0..3
    const int lane = tid & 63;
    const int qm   = lane >> 5;                // quad row-pair (0/1)
    const int qc   = lane & 31;                // quad col

    f32x4 acc[12];
#pragma unroll
    for (int j = 0; j < 12; ++j)
#pragma unroll
        for (int p = 0; p < 4; ++p) acc[j][p] = 0.f;

    const float* wbase = wlds + outq * 12 * 64;
    for (int cg = 0; cg < 16; ++cg) {          // 4-ci groups
        float4 xv[4];
#pragma unroll
        for (int u = 0; u < 4; ++u)
            xv[u] = *(const float4*)(xs + (cg * 4 + u) * 256 + lane * 4);
#pragma unroll
        for (int j = 0; j < 12; ++j) {
            float4 w4 = *(const float4*)(wbase + j * 64 + cg * 4);  // broadcast
            acc[j][0] += w4.x * xv[0].x + w4.y * xv[1].x + w4.z * xv[2].x + w4.w * xv[3].x;
            acc[j][1] += w4.x * xv[0].y + w4.y * xv[1].y + w4.z * xv[2].y + w4.w * xv[3].y;
            acc[j][2] += w4.x * xv[0].z + w4.y * xv[1].z + w4.z * xv[2].z + w4.w * xv[3].z;
            acc[j][3] += w4.x * xv[0].w + w4.y * xv[1].w + w4.z * xv[2].w + w4.w * xv[3].w;
        }
    }

    const int px00 = (4 * rg + 2 * qm) * 64 + 2 * qc;       // quad origin px
    const int ps   = (2 * rg + qm) * 32 + qc;               // pooled index

    if (outq == 0) {
        // theta rows 0..7 (j=0..7), all 4 px, *log2e, packed b128 stores
        const int pxo[4] = {px00, px00 + 1, px00 + 64, px00 + 65};
#pragma unroll
        for (int p = 0; p < 4; ++p) {
            uint4 pkd;
            pkd.x = pk2(acc[0][p] * LOG2E, acc[1][p] * LOG2E);
            pkd.y = pk2(acc[2][p] * LOG2E, acc[3][p] * LOG2E);
            pkd.z = pk2(acc[4][p] * LOG2E, acc[5][p] * LOG2E);
            pkd.w = pk2(acc[6][p] * LOG2E, acc[7][p] * LOG2E);
            *(uint4*)(theta + ((size_t)b * HWs + pxo[p]) * 8) = pkd;
        }
    }
    // pooled outputs: out row oo = outq*12 + j; phi for 8<=oo<16, g for oo>=16
#pragma unroll
    for (int j = 0; j < 12; ++j) {
        const int oo = outq * 12 + j;
        if (oo < 8) continue;                  // theta handled above
        const float pm = fmaxf(fmaxf(acc[j][0], acc[j][1]), fmaxf(acc[j][2], acc[j][3]));
        if (oo < 16) phi[((size_t)b * NPS + ps) * 8 + (oo - 8)] = f2bf(pm);
        else         gT[((size_t)b * 32 + (oo - 16)) * NPS + ps] = f2bf(pm);
    }
}

// ---------------------------------------------------------------------------
// Kernel 2 (v4b): identical to round-6 v4 EXCEPT the launch bound.
// Round 6's __launch_bounds__(256,6) capped VGPRs at ~85 -> full spill
// (VGPR_Count=40, WRITE_SIZE 227 MB, duration = spill traffic / HBM BW).
// Default bound lets the pipeline live in registers.
// ---------------------------------------------------------------------------
__global__ __launch_bounds__(256) void k_attn(
    const float* __restrict__ x, const float* __restrict__ Wo,
    const float* __restrict__ gamma_p, const unsigned short* __restrict__ ws,
    float* __restrict__ out)
{
    __shared__ __align__(16) unsigned char smem[18432];
    // P: wave*4608B (2 bufs x 16q x 72s x 2B). After sync: otile f32[32][36]
    // at byte 0 (4608B); combine area at byte 8192 (2 x 64 x 12 f32 = 6144B).

    const int tid  = threadIdx.x;
    const int wave = __builtin_amdgcn_readfirstlane(tid >> 6);
    const int lane = tid & 63;
    const int quad = lane >> 4, lr = lane & 15;
    const int blk  = blockIdx.x;
    const int b    = blk >> 7;
    const int q0   = (blk & 127) * 32;
    const int qh   = wave >> 1;                // q-half (0/1)
    const int sh   = wave & 1;                 // s-half (0/1)
    const int qw0  = q0 + qh * 16;

    const unsigned short* th = ws + (size_t)b * HWs * 8;
    const unsigned short* ph = ws + PHI_OFF + (size_t)b * NPS * 8;
    const unsigned short* gp = ws + GT_OFF + (size_t)b * 32 * NPS;
    unsigned short* Pw = (unsigned short*)smem + wave * 2304;   // 2 x 1152 ushorts

    const s16x8 zf = {0, 0, 0, 0, 0, 0, 0, 0};

    s16x8 thA = zf;
    if (quad == 0) thA = LD8G(th + (size_t)(qw0 + lr) * 8);

    f32x4 O[2];
    f32x4 l4;
#pragma unroll
    for (int r = 0; r < 4; ++r) { O[0][r] = 0.f; O[1][r] = 0.f; l4[r] = 0.f; }

    s16x8 phB[4] = {zf, zf, zf, zf};           // quads 1-3 stay zero forever

    const unsigned short* php = ph + (size_t)(sh * 512 + lr) * 8;
    const unsigned short* gb0 = gp + (size_t)lr * NPS + sh * 512 + quad * 8;
    const unsigned short* gb1 = gb0 + 16 * NPS;
    const f32x4 zc = {0.f, 0.f, 0.f, 0.f};

#pragma unroll
    for (int i = 0; i < 8; ++i) {
        // phi B-frags for tile i (exec-masked: only quad 0 carries data)
        if (quad == 0) {
            phB[0] = LD8G(php + 0);
            phB[1] = LD8G(php + 128);
            phB[2] = LD8G(php + 256);
            phB[3] = LD8G(php + 384);
        }
        php += 512;

        // lagged PV for tile i-1 (Gf + Pf loads issue early)
        if (i > 0) {
            s16x8 Gf0a = LD8G(gb0), Gf0b = LD8G(gb0 + 32);
            s16x8 Gf1a = LD8G(gb1), Gf1b = LD8G(gb1 + 32);
            const unsigned short* Pb = Pw + ((i - 1) & 1) * 1152 + lr * 72 + quad * 8;
            s16x8 Pf0 = *(const s16x8*)(Pb);
            s16x8 Pf1 = *(const s16x8*)(Pb + 32);
            O[0] = __builtin_amdgcn_mfma_f32_16x16x32_bf16(Pf0, Gf0a, O[0], 0, 0, 0);
            O[1] = __builtin_amdgcn_mfma_f32_16x16x32_bf16(Pf0, Gf1a, O[1], 0, 0, 0);
            O[0] = __builtin_amdgcn_mfma_f32_16x16x32_bf16(Pf1, Gf0b, O[0], 0, 0, 0);
            O[1] = __builtin_amdgcn_mfma_f32_16x16x32_bf16(Pf1, Gf1b, O[1], 0, 0, 0);
            gb0 += 64; gb1 += 64;
        }

        // scores tile i: D[q=quad*4+r][s=ss*16+lr]
        f32x4 S[4];
#pragma unroll
        for (int ss = 0; ss < 4; ++ss)
            S[ss] = __builtin_amdgcn_mfma_f32_16x16x32_bf16(thA, phB[ss], zc, 0, 0, 0);

        // p = exp2(S), accumulate l, store bf16 P to buf i&1
        unsigned short* Pbw = Pw + (i & 1) * 1152 + quad * 288 + lr;
#pragma unroll
        for (int ss = 0; ss < 4; ++ss)
#pragma unroll
            for (int r = 0; r < 4; ++r) {
                const float p = exp2f(S[ss][r]);
                l4[r] += p;
                Pbw[r * 72 + ss * 16] = (unsigned short)(__float_as_uint(p) >> 16);
            }
    }
    // drain: PV for tile 7 (buf 1; gb at tile-7 position)
    {
        s16x8 Gf0a = LD8G(gb0), Gf0b = LD8G(gb0 + 32);
        s16x8 Gf1a = LD8G(gb1), Gf1b = LD8G(gb1 + 32);
        const unsigned short* Pb = Pw + 1152 + lr * 72 + quad * 8;
        s16x8 Pf0 = *(const s16x8*)(Pb);
        s16x8 Pf1 = *(const s16x8*)(Pb + 32);
        O[0] = __builtin_amdgcn_mfma_f32_16x16x32_bf16(Pf0, Gf0a, O[0], 0, 0, 0);
        O[1] = __builtin_amdgcn_mfma_f32_16x16x32_bf16(Pf0, Gf1a, O[1], 0, 0, 0);
        O[0] = __builtin_amdgcn_mfma_f32_16x16x32_bf16(Pf1, Gf0b, O[0], 0, 0, 0);
        O[1] = __builtin_amdgcn_mfma_f32_16x16x32_bf16(Pf1, Gf1b, O[1], 0, 0, 0);
    }

    // ---- combine s-halves: sh1 publishes partials, sh0 adds ----
    float* comb = (float*)(smem + 8192);       // [qh][lane][12]
    __syncthreads();
    if (sh == 1) {
        float* c = comb + (size_t)(qh * 64 + lane) * 12;
        *(f32x4*)(c)     = O[0];
        *(f32x4*)(c + 4) = O[1];
        *(f32x4*)(c + 8) = l4;
    }
    __syncthreads();
    if (sh == 0) {
        const float* c = comb + (size_t)(qh * 64 + lane) * 12;
        f32x4 o0 = *(const f32x4*)(c);
        f32x4 o1 = *(const f32x4*)(c + 4);
        f32x4 lb = *(const f32x4*)(c + 8);
#pragma unroll
        for (int r = 0; r < 4; ++r) {
            O[0][r] += o0[r]; O[1][r] += o1[r]; l4[r] += lb[r];
        }
        // butterfly l over the 16-lane s-groups, then normalize
        f32x4 linv;
#pragma unroll
        for (int r = 0; r < 4; ++r) {
            float v = l4[r];
            v += __shfl_xor(v, 1);
            v += __shfl_xor(v, 2);
            v += __shfl_xor(v, 4);
            v += __shfl_xor(v, 8);
            linv[r] = 1.f / v;
        }
        float* otile = (float*)smem;           // [32 c][36 q-stride]
#pragma unroll
        for (int cs = 0; cs < 2; ++cs) {
            f32x4 v;
#pragma unroll
            for (int r = 0; r < 4; ++r) v[r] = O[cs][r] * linv[r];
            *(f32x4*)(otile + (cs * 16 + lr) * 36 + qh * 16 + quad * 4) = v;
        }
    }
    __syncthreads();

    // ---- Wo epilogue + residual: wave owns 16 oc rows; lane q = lane&31 ----
    const float* otile = (const float*)smem;
    const int qq = lane & 31;                  // upper half-wave duplicates
    float otcol[32];
#pragma unroll
    for (int c = 0; c < 32; ++c) otcol[c] = otile[c * 36 + qq];
    const float* wrow = Wo + wave * 16 * 32;   // scalar (wave uniform)
    const float gam = gamma_p[0];
#pragma unroll
    for (int j = 0; j < 16; ++j) {
        float acc = 0.f;
#pragma unroll
        for (int c = 0; c < 32; ++c) acc += wrow[j * 32 + c] * otcol[c];
        if (lane < 32) {
            const size_t a = ((size_t)b * NC + wave * 16 + j) * HWs + q0 + qq;
            out[a] = gam * acc + x[a];
        }
    }
}

extern "C" void kernel_launch(void* const* d_in, const int* in_sizes, int n_in,
                              void* d_out, int out_size, void* d_ws, size_t ws_size,
                              hipStream_t stream) {
    const float* x     = (const float*)d_in[0];
    const float* Wt    = (const float*)d_in[1];
    const float* Wp    = (const float*)d_in[2];
    const float* Wg    = (const float*)d_in[3];
    const float* Wo    = (const float*)d_in[4];
    const float* gamma = (const float*)d_in[5];
    float* out = (float*)d_out;
    unsigned short* ws = (unsigned short*)d_ws;

    k_proj<<<256, 256, 0, stream>>>(x, Wt, Wp, Wg, ws);
    k_attn<<<2048, 256, 0, stream>>>(x, Wo, gamma, ws, out);
}

// Round 8
// 134.293 us; speedup vs baseline: 1.4862x; 1.0575x over previous
//
#include <hip/hip_runtime.h>
#include <math.h>

// Problem constants
#define NB   16
#define NC   64
#define HWs  4096
#define NPS  1024
#define LOG2E 1.44269504088896341f

// ws layout in ushort (bf16 bit patterns)
static constexpr size_t PHI_OFF = (size_t)NB * HWs * 8;            // theta: [b][4096][8]
static constexpr size_t GT_OFF  = PHI_OFF + (size_t)NB * NPS * 8;  // phi:   [b][1024][8]
static constexpr size_t Z_OFF   = GT_OFF + (size_t)NB * 32 * NPS;  // gT:    [b][32][1024] (s-permuted per 64-tile)
// Z_OFF: 8 ushorts of zeros (zero-source for quads 1-3 fragment loads)

typedef short s16x8 __attribute__((ext_vector_type(8)));
typedef float f32x4 __attribute__((ext_vector_type(4)));

#define LD8G(p) (*(const s16x8*)(p))

__device__ inline unsigned short f2bf(float f) {
    unsigned int u = __float_as_uint(f);
    u += 0x7fffu + ((u >> 16) & 1u);          // RNE
    return (unsigned short)(u >> 16);
}
__device__ inline unsigned int pk2(float a, float b) {
    unsigned int ua = __float_as_uint(a); ua += 0x7fffu + ((ua >> 16) & 1u);
    unsigned int ub = __float_as_uint(b); ub += 0x7fffu + ((ub >> 16) & 1u);
    return (ua >> 16) | (ub & 0xffff0000u);
}

// ---------------------------------------------------------------------------
// Kernel 1 (v5): register-tiled projection GEMM (= r7 v4) with two edits:
//  - gT columns stored s-PERMUTED within each 64-tile: col' = base64 +
//    (w&15)*4 + (w>>4), matching k_attn's packed-P LDS layout so PV
//    contracts both operands over the same permutation.
//  - writes a 16B zero block at Z_OFF (k_attn's zero-source fragments).
// ---------------------------------------------------------------------------
__global__ __launch_bounds__(256) void k_proj(
    const float* __restrict__ x, const float* __restrict__ Wt,
    const float* __restrict__ Wp, const float* __restrict__ Wg,
    unsigned short* __restrict__ ws)
{
    __shared__ __align__(16) float xs[64 * 256];   // 64 KB, [ci][quad*4+sub]
    __shared__ __align__(16) float wlds[48 * 64];  // 12 KB: rows 0-7 Wt, 8-15 Wp, 16-47 Wg

    unsigned short* theta = ws;
    unsigned short* phi   = ws + PHI_OFF;
    unsigned short* gT    = ws + GT_OFF;

    const int tid = threadIdx.x;
    const int blk = blockIdx.x;
    const int b   = blk >> 4;
    const int rg  = blk & 15;                  // image rows 4rg..4rg+3

    if (blk == 0 && tid == 0)
        *(uint4*)(ws + Z_OFF) = make_uint4(0u, 0u, 0u, 0u);   // zero-source

    // ---- stage weights ----
    {
        float4* wl4 = (float4*)wlds;
        if (tid < 128) wl4[tid] = ((const float4*)Wt)[tid];
        else           wl4[tid] = ((const float4*)Wp)[tid - 128];
        wl4[256 + tid] = ((const float4*)Wg)[tid];
        wl4[512 + tid] = ((const float4*)Wg)[256 + tid];
    }
    // ---- stage x: slice x[b][ci][4rg*64 .. +256) -> pool-quad-major ----
    const float* xsrc = x + (size_t)b * NC * HWs + rg * 256;
#pragma unroll
    for (int i = 0; i < 16; ++i) {
        const int f  = i * 256 + tid;          // f4 index, 0..4095
        const int ci = f >> 6;
        const int c4 = f & 63;
        float4 v = *(const float4*)(xsrc + (size_t)ci * HWs + c4 * 4);
        const int e0 = 4 * c4;                 // linear px-in-slice of v.x
        const int r  = e0 >> 6;                // row within group (0..3)
        const int c0 = e0 & 63;
        const int qm = r >> 1, dy = r & 1;
        const int q0i = qm * 32 + (c0 >> 1);   // quad of (v.x,v.y)
        float* base = xs + ci * 256;
        *(float2*)(base + q0i * 4 + dy * 2)       = make_float2(v.x, v.y);
        *(float2*)(base + (q0i + 1) * 4 + dy * 2) = make_float2(v.z, v.w);
    }
    __syncthreads();

    const int outq = __builtin_amdgcn_readfirstlane(tid >> 6);  // 0..3
    const int lane = tid & 63;
    const int qm   = lane >> 5;                // quad row-pair (0/1)
    const int qc   = lane & 31;                // quad col

    f32x4 acc[12];
#pragma unroll
    for (int j = 0; j < 12; ++j)
#pragma unroll
        for (int p = 0; p < 4; ++p) acc[j][p] = 0.f;

    const float* wbase = wlds + outq * 12 * 64;
    for (int cg = 0; cg < 16; ++cg) {          // 4-ci groups
        float4 xv[4];
#pragma unroll
        for (int u = 0; u < 4; ++u)
            xv[u] = *(const float4*)(xs + (cg * 4 + u) * 256 + lane * 4);
#pragma unroll
        for (int j = 0; j < 12; ++j) {
            float4 w4 = *(const float4*)(wbase + j * 64 + cg * 4);  // broadcast
            acc[j][0] += w4.x * xv[0].x + w4.y * xv[1].x + w4.z * xv[2].x + w4.w * xv[3].x;
            acc[j][1] += w4.x * xv[0].y + w4.y * xv[1].y + w4.z * xv[2].y + w4.w * xv[3].y;
            acc[j][2] += w4.x * xv[0].z + w4.y * xv[1].z + w4.z * xv[2].z + w4.w * xv[3].z;
            acc[j][3] += w4.x * xv[0].w + w4.y * xv[1].w + w4.z * xv[2].w + w4.w * xv[3].w;
        }
    }

    const int px00 = (4 * rg + 2 * qm) * 64 + 2 * qc;       // quad origin px
    const int ps   = (2 * rg + qm) * 32 + qc;               // pooled index
    const int psP  = (ps & ~63) | (((ps & 15) << 2) | ((ps >> 4) & 3));  // s-perm

    if (outq == 0) {
        // theta rows 0..7 (j=0..7), all 4 px, *log2e, packed b128 stores
        const int pxo[4] = {px00, px00 + 1, px00 + 64, px00 + 65};
#pragma unroll
        for (int p = 0; p < 4; ++p) {
            uint4 pkd;
            pkd.x = pk2(acc[0][p] * LOG2E, acc[1][p] * LOG2E);
            pkd.y = pk2(acc[2][p] * LOG2E, acc[3][p] * LOG2E);
            pkd.z = pk2(acc[4][p] * LOG2E, acc[5][p] * LOG2E);
            pkd.w = pk2(acc[6][p] * LOG2E, acc[7][p] * LOG2E);
            *(uint4*)(theta + ((size_t)b * HWs + pxo[p]) * 8) = pkd;
        }
    }
    // pooled outputs: out row oo = outq*12 + j; phi for 8<=oo<16, g for oo>=16
#pragma unroll
    for (int j = 0; j < 12; ++j) {
        const int oo = outq * 12 + j;
        if (oo < 8) continue;                  // theta handled above
        const float pm = fmaxf(fmaxf(acc[j][0], acc[j][1]), fmaxf(acc[j][2], acc[j][3]));
        if (oo < 16) phi[((size_t)b * NPS + ps) * 8 + (oo - 8)] = f2bf(pm);
        else         gT[((size_t)b * 32 + (oo - 16)) * NPS + psP] = f2bf(pm);
    }
}

// ---------------------------------------------------------------------------
// Kernel 2 (v5): monolithic MFMA attention (r5-v3 shape: 1024 blocks,
// wave = 16 q, 16 key-tiles) with the VALU/LDS fat removed:
//  - raw v_exp_f32 (__builtin_amdgcn_exp2f) instead of OCML exp2f
//  - zero-source pointers (stride 0) for quads 1-3: NO masks in the loop
//  - P stored as packed dwords, 4x ds_write_b64/tile, s-permuted row layout
//    [j' -> s = (j'>>2)+(j'&3)*16], rows 144B (16B-aligned b128 reads);
//    gT is permuted identically by k_proj, so PV is contraction-equivalent.
//  - Gf prefetched one full tile ahead; loop fully unrolled.
// ---------------------------------------------------------------------------
__global__ __launch_bounds__(256) void k_attn(
    const float* __restrict__ x, const float* __restrict__ Wo,
    const float* __restrict__ gamma_p, const unsigned short* __restrict__ ws,
    float* __restrict__ out)
{
    __shared__ __align__(16) unsigned char smem[18432];
    // P: 4 waves x 2 bufs x 16 rows x 144B = 18432B. Epilogue: otile[32][68] f32 (8704B, reused).

    const int tid  = threadIdx.x;
    const int wave = __builtin_amdgcn_readfirstlane(tid >> 6);
    const int lane = tid & 63;
    const int quad = lane >> 4, lr = lane & 15;
    const int blk  = blockIdx.x;
    const int b    = blk >> 6;
    const int q0   = (blk & 63) * 64;
    const int qw0  = q0 + wave * 16;

    const unsigned short* th = ws + (size_t)b * HWs * 8;
    const unsigned short* ph = ws + PHI_OFF + (size_t)b * NPS * 8;
    const unsigned short* gp = ws + GT_OFF + (size_t)b * 32 * NPS;
    unsigned short* Pw = (unsigned short*)smem + wave * 2304;   // 2 bufs x 16 x 72 ushorts

    const s16x8 zf = {0, 0, 0, 0, 0, 0, 0, 0};

    // theta A-fragment: A[m=q=lr][k=quad*8+j], real k<8 in quad 0 (one-time mask ok)
    s16x8 thA = zf;
    if (quad == 0) thA = LD8G(th + (size_t)(qw0 + lr) * 8);

    // zero-source pointer trick: quads 1-3 read the 16B zeros at Z_OFF, stride 0
    const unsigned short* php;
    int fstep, tstep;
    if (quad == 0) { php = ph + (size_t)lr * 8; fstep = 128; tstep = 512; }
    else           { php = ws + Z_OFF;          fstep = 0;   tstep = 0;   }

    const unsigned short* gb0 = gp + (size_t)lr * NPS + quad * 8;   // c = lr
    const unsigned short* gb1 = gb0 + (size_t)16 * NPS;             // c = 16+lr

    f32x4 O[2];
    f32x4 l4;
#pragma unroll
    for (int r = 0; r < 4; ++r) { O[0][r] = 0.f; O[1][r] = 0.f; l4[r] = 0.f; }

    s16x8 Gc[4], Gn[4];                        // [kc*2+cs], current / next
    const f32x4 zc = {0.f, 0.f, 0.f, 0.f};

#pragma unroll
    for (int t = 0; t < 16; ++t) {
        // ---- load phi B-frags for tile t (no masks: zero-source lanes) ----
        s16x8 phB[4];
        phB[0] = LD8G(php);
        phB[1] = LD8G(php + fstep);
        phB[2] = LD8G(php + 2 * fstep);
        phB[3] = LD8G(php + 3 * fstep);
        php += tstep;

        // ---- prefetch Gf for tile t (consumed by PV at iter t+1) ----
        Gn[0] = LD8G(gb0);        // kc=0, cs=0
        Gn[1] = LD8G(gb1);        // kc=0, cs=1
        Gn[2] = LD8G(gb0 + 32);   // kc=1, cs=0
        Gn[3] = LD8G(gb1 + 32);   // kc=1, cs=1
        gb0 += 64; gb1 += 64;

        // ---- lagged PV for tile t-1 (P from buf (t-1)&1, Gc from iter t-1) ----
        if (t > 0) {
            const unsigned short* Pb = Pw + ((t - 1) & 1) * 1152 + lr * 72 + quad * 8;
            s16x8 Pf0 = *(const s16x8*)(Pb);
            s16x8 Pf1 = *(const s16x8*)(Pb + 32);
            O[0] = __builtin_amdgcn_mfma_f32_16x16x32_bf16(Pf0, Gc[0], O[0], 0, 0, 0);
            O[1] = __builtin_amdgcn_mfma_f32_16x16x32_bf16(Pf0, Gc[1], O[1], 0, 0, 0);
            O[0] = __builtin_amdgcn_mfma_f32_16x16x32_bf16(Pf1, Gc[2], O[0], 0, 0, 0);
            O[1] = __builtin_amdgcn_mfma_f32_16x16x32_bf16(Pf1, Gc[3], O[1], 0, 0, 0);
        }

        // ---- scores tile t: D[q=quad*4+r][s=ss*16+lr] ----
        f32x4 S[4];
#pragma unroll
        for (int ss = 0; ss < 4; ++ss)
            S[ss] = __builtin_amdgcn_mfma_f32_16x16x32_bf16(thA, phB[ss], zc, 0, 0, 0);

        // ---- p = exp2(S) raw; packed b64 stores to buf t&1 (s-permuted rows) ----
        unsigned short* Pbw = Pw + (t & 1) * 1152;
#pragma unroll
        for (int r = 0; r < 4; ++r) {
            const float p0 = __builtin_amdgcn_exp2f(S[0][r]);
            const float p1 = __builtin_amdgcn_exp2f(S[1][r]);
            const float p2 = __builtin_amdgcn_exp2f(S[2][r]);
            const float p3 = __builtin_amdgcn_exp2f(S[3][r]);
            l4[r] += (p0 + p1) + (p2 + p3);
            uint2 pw;   // truncate to bf16; row ushort u=4lr+d <-> s=(u>>2)+(u&3)*16
            pw.x = (__float_as_uint(p0) >> 16) | (__float_as_uint(p1) & 0xffff0000u);
            pw.y = (__float_as_uint(p2) >> 16) | (__float_as_uint(p3) & 0xffff0000u);
            *(uint2*)(Pbw + (quad * 4 + r) * 72 + lr * 4) = pw;
        }

        Gc[0] = Gn[0]; Gc[1] = Gn[1]; Gc[2] = Gn[2]; Gc[3] = Gn[3];
    }
    // ---- drain: PV for tile 15 ----
    {
        const unsigned short* Pb = Pw + 1152 + lr * 72 + quad * 8;
        s16x8 Pf0 = *(const s16x8*)(Pb);
        s16x8 Pf1 = *(const s16x8*)(Pb + 32);
        O[0] = __builtin_amdgcn_mfma_f32_16x16x32_bf16(Pf0, Gc[0], O[0], 0, 0, 0);
        O[1] = __builtin_amdgcn_mfma_f32_16x16x32_bf16(Pf0, Gc[1], O[1], 0, 0, 0);
        O[0] = __builtin_amdgcn_mfma_f32_16x16x32_bf16(Pf1, Gc[2], O[0], 0, 0, 0);
        O[1] = __builtin_amdgcn_mfma_f32_16x16x32_bf16(Pf1, Gc[3], O[1], 0, 0, 0);
    }

    // l: butterfly-sum partials over the 16 s-group lanes (same q map as O)
    f32x4 linv;
#pragma unroll
    for (int r = 0; r < 4; ++r) {
        float v = l4[r];
        v += __shfl_xor(v, 1);
        v += __shfl_xor(v, 2);
        v += __shfl_xor(v, 4);
        v += __shfl_xor(v, 8);
        linv[r] = 1.f / v;
    }

    __syncthreads();                          // all waves done with their Pw
    float* otile = (float*)smem;              // [32 c][68 q-stride]
#pragma unroll
    for (int cs = 0; cs < 2; ++cs) {
        f32x4 v;
#pragma unroll
        for (int r = 0; r < 4; ++r) v[r] = O[cs][r] * linv[r];
        *(f32x4*)(otile + (cs * 16 + lr) * 68 + wave * 16 + quad * 4) = v;
    }
    __syncthreads();

    // Wo epilogue + residual: thread = (q = tid&63, oc quarter = tid>>6)
    const int qq = tid & 63;
    const int quarter = __builtin_amdgcn_readfirstlane(tid >> 6);
    float acc[16];
#pragma unroll
    for (int j = 0; j < 16; ++j) acc[j] = 0.f;
    for (int c = 0; c < 32; ++c) {
        const float ov = otile[c * 68 + qq];
#pragma unroll
        for (int j = 0; j < 16; ++j)
            acc[j] += Wo[(quarter * 16 + j) * 32 + c] * ov;   // wave-uniform
    }
    const float gam = gamma_p[0];
#pragma unroll
    for (int j = 0; j < 16; ++j) {
        const size_t a = ((size_t)b * NC + quarter * 16 + j) * HWs + q0 + qq;
        out[a] = gam * acc[j] + x[a];
    }
}

extern "C" void kernel_launch(void* const* d_in, const int* in_sizes, int n_in,
                              void* d_out, int out_size, void* d_ws, size_t ws_size,
                              hipStream_t stream) {
    const float* x     = (const float*)d_in[0];
    const float* Wt    = (const float*)d_in[1];
    const float* Wp    = (const float*)d_in[2];
    const float* Wg    = (const float*)d_in[3];
    const float* Wo    = (const float*)d_in[4];
    const float* gamma = (const float*)d_in[5];
    float* out = (float*)d_out;
    unsigned short* ws = (unsigned short*)d_ws;

    k_proj<<<256, 256, 0, stream>>>(x, Wt, Wp, Wg, ws);
    k_attn<<<1024, 256, 0, stream>>>(x, Wo, gamma, ws, out);
}

// Round 9
// 134.224 us; speedup vs baseline: 1.4869x; 1.0005x over previous
//
#include <hip/hip_runtime.h>
#include <math.h>

// Problem constants
#define NB   16
#define NC   64
#define HWs  4096
#define NPS  1024
#define LOG2E 1.44269504088896341f

// ws layout in ushort (bf16 bit patterns)
static constexpr size_t PHI_OFF = (size_t)NB * HWs * 8;            // theta: [b][4096][8]
static constexpr size_t GT_OFF  = PHI_OFF + (size_t)NB * NPS * 8;  // phi:   [b][1024][8]
static constexpr size_t Z_OFF   = GT_OFF + (size_t)NB * 32 * NPS;  // gT:    [b][32][1024] (s-permuted per 64-tile)

typedef short s16x8 __attribute__((ext_vector_type(8)));
typedef float f32x4 __attribute__((ext_vector_type(4)));

#define LD8G(p) (*(const s16x8*)(p))

__device__ inline unsigned short f2bf(float f) {
    unsigned int u = __float_as_uint(f);
    u += 0x7fffu + ((u >> 16) & 1u);          // RNE
    return (unsigned short)(u >> 16);
}
__device__ inline unsigned int pk2(float a, float b) {
    unsigned int ua = __float_as_uint(a); ua += 0x7fffu + ((ua >> 16) & 1u);
    unsigned int ub = __float_as_uint(b); ub += 0x7fffu + ((ub >> 16) & 1u);
    return (ua >> 16) | (ub & 0xffff0000u);
}

// ---------------------------------------------------------------------------
// Kernel 1 (v5, unchanged from round 8 — passing, ~5 us by residue model).
// ---------------------------------------------------------------------------
__global__ __launch_bounds__(256) void k_proj(
    const float* __restrict__ x, const float* __restrict__ Wt,
    const float* __restrict__ Wp, const float* __restrict__ Wg,
    unsigned short* __restrict__ ws)
{
    __shared__ __align__(16) float xs[64 * 256];   // 64 KB, [ci][quad*4+sub]
    __shared__ __align__(16) float wlds[48 * 64];  // 12 KB

    unsigned short* theta = ws;
    unsigned short* phi   = ws + PHI_OFF;
    unsigned short* gT    = ws + GT_OFF;

    const int tid = threadIdx.x;
    const int blk = blockIdx.x;
    const int b   = blk >> 4;
    const int rg  = blk & 15;

    if (blk == 0 && tid == 0)
        *(uint4*)(ws + Z_OFF) = make_uint4(0u, 0u, 0u, 0u);

    {
        float4* wl4 = (float4*)wlds;
        if (tid < 128) wl4[tid] = ((const float4*)Wt)[tid];
        else           wl4[tid] = ((const float4*)Wp)[tid - 128];
        wl4[256 + tid] = ((const float4*)Wg)[tid];
        wl4[512 + tid] = ((const float4*)Wg)[256 + tid];
    }
    const float* xsrc = x + (size_t)b * NC * HWs + rg * 256;
#pragma unroll
    for (int i = 0; i < 16; ++i) {
        const int f  = i * 256 + tid;
        const int ci = f >> 6;
        const int c4 = f & 63;
        float4 v = *(const float4*)(xsrc + (size_t)ci * HWs + c4 * 4);
        const int e0 = 4 * c4;
        const int r  = e0 >> 6;
        const int c0 = e0 & 63;
        const int qm = r >> 1, dy = r & 1;
        const int q0i = qm * 32 + (c0 >> 1);
        float* base = xs + ci * 256;
        *(float2*)(base + q0i * 4 + dy * 2)       = make_float2(v.x, v.y);
        *(float2*)(base + (q0i + 1) * 4 + dy * 2) = make_float2(v.z, v.w);
    }
    __syncthreads();

    const int outq = __builtin_amdgcn_readfirstlane(tid >> 6);
    const int lane = tid & 63;
    const int qm   = lane >> 5;
    const int qc   = lane & 31;

    f32x4 acc[12];
#pragma unroll
    for (int j = 0; j < 12; ++j)
#pragma unroll
        for (int p = 0; p < 4; ++p) acc[j][p] = 0.f;

    const float* wbase = wlds + outq * 12 * 64;
    for (int cg = 0; cg < 16; ++cg) {
        float4 xv[4];
#pragma unroll
        for (int u = 0; u < 4; ++u)
            xv[u] = *(const float4*)(xs + (cg * 4 + u) * 256 + lane * 4);
#pragma unroll
        for (int j = 0; j < 12; ++j) {
            float4 w4 = *(const float4*)(wbase + j * 64 + cg * 4);
            acc[j][0] += w4.x * xv[0].x + w4.y * xv[1].x + w4.z * xv[2].x + w4.w * xv[3].x;
            acc[j][1] += w4.x * xv[0].y + w4.y * xv[1].y + w4.z * xv[2].y + w4.w * xv[3].y;
            acc[j][2] += w4.x * xv[0].z + w4.y * xv[1].z + w4.z * xv[2].z + w4.w * xv[3].z;
            acc[j][3] += w4.x * xv[0].w + w4.y * xv[1].w + w4.z * xv[2].w + w4.w * xv[3].w;
        }
    }

    const int px00 = (4 * rg + 2 * qm) * 64 + 2 * qc;
    const int ps   = (2 * rg + qm) * 32 + qc;
    const int psP  = (ps & ~63) | (((ps & 15) << 2) | ((ps >> 4) & 3));

    if (outq == 0) {
        const int pxo[4] = {px00, px00 + 1, px00 + 64, px00 + 65};
#pragma unroll
        for (int p = 0; p < 4; ++p) {
            uint4 pkd;
            pkd.x = pk2(acc[0][p] * LOG2E, acc[1][p] * LOG2E);
            pkd.y = pk2(acc[2][p] * LOG2E, acc[3][p] * LOG2E);
            pkd.z = pk2(acc[4][p] * LOG2E, acc[5][p] * LOG2E);
            pkd.w = pk2(acc[6][p] * LOG2E, acc[7][p] * LOG2E);
            *(uint4*)(theta + ((size_t)b * HWs + pxo[p]) * 8) = pkd;
        }
    }
#pragma unroll
    for (int j = 0; j < 12; ++j) {
        const int oo = outq * 12 + j;
        if (oo < 8) continue;
        const float pm = fmaxf(fmaxf(acc[j][0], acc[j][1]), fmaxf(acc[j][2], acc[j][3]));
        if (oo < 16) phi[((size_t)b * NPS + ps) * 8 + (oo - 8)] = f2bf(pm);
        else         gT[((size_t)b * 32 + (oo - 16)) * NPS + psP] = f2bf(pm);
    }
}

// ---------------------------------------------------------------------------
// Kernel 2 (v6): MFMA attention with block-shared LDS staging of phi/gT.
// r8 was 70% stall: per-wave fragment loads from L2 (~200-300 cyc) with 4x
// redundancy across the block's waves. v6 stages each tile's phi (1KB) +
// gT (4.5KB padded) into double-buffered LDS once per block (b128 loads +
// b128 ds_writes, 1 barrier/tile); fragment reads become ds_read_b128.
// Gf(t) read to regs in iter t, consumed by lagged PV in iter t+1 (so the
// staging buffer being overwritten is never read). P path / s-permutation /
// epilogue byte-identical to r8 (passing).
// LDS: [0,18432) P (wave*4608, 2 bufs x 16 x 144B)
//      [18432,20480) phiS (2 bufs x 64 x 16B)
//      [20480,29696) gS   (2 bufs x 32 x 144B)
//      [29696,29712) zero16
// ---------------------------------------------------------------------------
__global__ __launch_bounds__(256) void k_attn(
    const float* __restrict__ x, const float* __restrict__ Wo,
    const float* __restrict__ gamma_p, const unsigned short* __restrict__ ws,
    float* __restrict__ out)
{
    __shared__ __align__(16) unsigned char smem[29952];

    const int tid  = threadIdx.x;
    const int wave = __builtin_amdgcn_readfirstlane(tid >> 6);
    const int lane = tid & 63;
    const int quad = lane >> 4, lr = lane & 15;
    const int blk  = blockIdx.x;
    const int b    = blk >> 6;
    const int q0   = (blk & 63) * 64;
    const int qw0  = q0 + wave * 16;

    const unsigned short* th = ws + (size_t)b * HWs * 8;
    const unsigned short* ph = ws + PHI_OFF + (size_t)b * NPS * 8;
    const unsigned short* gp = ws + GT_OFF + (size_t)b * 32 * NPS;

    unsigned short* Pw = (unsigned short*)smem + wave * 2304;   // ushort units

    // staging source/dest (per thread): gT chunk (c = tid>>3, seg = tid&7)
    const int sc   = tid >> 3;
    const int sseg = tid & 7;
    const unsigned short* gsrc = gp + (size_t)sc * NPS + sseg * 8;
    const unsigned short* psrc = ph + (size_t)tid * 8;           // tid<64 only
    unsigned char* gdstB = smem + 20480 + sc * 144 + sseg * 16;  // + buf*4608
    unsigned char* pdstB = smem + 18432 + tid * 16;              // + buf*1024

    if (tid < 4) ((unsigned int*)(smem + 29696))[tid] = 0u;      // zero block

    // ---- pre-stage tile 0 into buf 0 ----
    {
        uint4 gv = *(const uint4*)(gsrc);
        *(uint4*)(gdstB) = gv;
        if (tid < 64) {
            uint4 pv = *(const uint4*)(psrc);
            *(uint4*)(pdstB) = pv;
        }
    }

    const s16x8 zf = {0, 0, 0, 0, 0, 0, 0, 0};
    s16x8 thA = zf;
    if (quad == 0) thA = LD8G(th + (size_t)(qw0 + lr) * 8);

    // per-lane LDS fragment-read bases
    const int phb_base    = (quad == 0) ? (18432 + lr * 16) : 29696;
    const int phb_bufstep = (quad == 0) ? 1024 : 0;
    const int phb_ssstep  = (quad == 0) ? 256  : 0;
    const int g_base      = 20480 + lr * 144 + quad * 16;

    f32x4 O[2];
    f32x4 l4;
#pragma unroll
    for (int r = 0; r < 4; ++r) { O[0][r] = 0.f; O[1][r] = 0.f; l4[r] = 0.f; }

    s16x8 Gc[4], Gn[4];
    const f32x4 zc = {0.f, 0.f, 0.f, 0.f};

    __syncthreads();                           // tile 0 staged

#pragma unroll
    for (int t = 0; t < 16; ++t) {
        const int buf  = t & 1;
        const int nbuf = buf ^ 1;

        // 1. issue staging global loads for tile t+1 (written in step 6)
        uint4 gv = {0,0,0,0}, pv = {0,0,0,0};
        if (t < 15) {
            gv = *(const uint4*)(gsrc + (t + 1) * 64);
            if (tid < 64) pv = *(const uint4*)(psrc + (t + 1) * 512);
        }

        // 2. fragment reads from LDS buf t&1
        const unsigned char* pb = smem + phb_base + buf * phb_bufstep;
        s16x8 phB0 = *(const s16x8*)(pb);
        s16x8 phB1 = *(const s16x8*)(pb + phb_ssstep);
        s16x8 phB2 = *(const s16x8*)(pb + 2 * phb_ssstep);
        s16x8 phB3 = *(const s16x8*)(pb + 3 * phb_ssstep);
        const unsigned char* gb = smem + g_base + buf * 4608;
        Gn[0] = *(const s16x8*)(gb);            // kc0, cs0 (c = lr)
        Gn[1] = *(const s16x8*)(gb + 2304);     // kc0, cs1 (c = 16+lr)
        Gn[2] = *(const s16x8*)(gb + 64);       // kc1, cs0
        Gn[3] = *(const s16x8*)(gb + 2304+64);  // kc1, cs1

        // 3. lagged PV for tile t-1 (own-wave P + Gc regs from iter t-1)
        if (t > 0) {
            const unsigned short* Pb = Pw + ((t - 1) & 1) * 1152 + lr * 72 + quad * 8;
            s16x8 Pf0 = *(const s16x8*)(Pb);
            s16x8 Pf1 = *(const s16x8*)(Pb + 32);
            O[0] = __builtin_amdgcn_mfma_f32_16x16x32_bf16(Pf0, Gc[0], O[0], 0, 0, 0);
            O[1] = __builtin_amdgcn_mfma_f32_16x16x32_bf16(Pf0, Gc[1], O[1], 0, 0, 0);
            O[0] = __builtin_amdgcn_mfma_f32_16x16x32_bf16(Pf1, Gc[2], O[0], 0, 0, 0);
            O[1] = __builtin_amdgcn_mfma_f32_16x16x32_bf16(Pf1, Gc[3], O[1], 0, 0, 0);
        }

        // 4. scores tile t: D[q=quad*4+r][s=ss*16+lr]
        f32x4 S[4];
        S[0] = __builtin_amdgcn_mfma_f32_16x16x32_bf16(thA, phB0, zc, 0, 0, 0);
        S[1] = __builtin_amdgcn_mfma_f32_16x16x32_bf16(thA, phB1, zc, 0, 0, 0);
        S[2] = __builtin_amdgcn_mfma_f32_16x16x32_bf16(thA, phB2, zc, 0, 0, 0);
        S[3] = __builtin_amdgcn_mfma_f32_16x16x32_bf16(thA, phB3, zc, 0, 0, 0);

        // 5. p = exp2(S) raw; packed b64 stores to P buf t&1 (s-permuted rows)
        unsigned short* Pbw = Pw + buf * 1152;
#pragma unroll
        for (int r = 0; r < 4; ++r) {
            const float p0 = __builtin_amdgcn_exp2f(S[0][r]);
            const float p1 = __builtin_amdgcn_exp2f(S[1][r]);
            const float p2 = __builtin_amdgcn_exp2f(S[2][r]);
            const float p3 = __builtin_amdgcn_exp2f(S[3][r]);
            l4[r] += (p0 + p1) + (p2 + p3);
            uint2 pw;
            pw.x = (__float_as_uint(p0) >> 16) | (__float_as_uint(p1) & 0xffff0000u);
            pw.y = (__float_as_uint(p2) >> 16) | (__float_as_uint(p3) & 0xffff0000u);
            *(uint2*)(Pbw + (quad * 4 + r) * 72 + lr * 4) = pw;
        }

        // 6. write staged tile t+1 into buf nbuf
        if (t < 15) {
            *(uint4*)(gdstB + nbuf * 4608) = gv;
            if (tid < 64) *(uint4*)(pdstB + nbuf * 1024) = pv;
        }

        // 7. rotate G
        Gc[0] = Gn[0]; Gc[1] = Gn[1]; Gc[2] = Gn[2]; Gc[3] = Gn[3];

        // 8. barrier: staged buf readable next iter; read-before-write safe
        __syncthreads();
    }
    // drain: PV for tile 15
    {
        const unsigned short* Pb = Pw + 1152 + lr * 72 + quad * 8;
        s16x8 Pf0 = *(const s16x8*)(Pb);
        s16x8 Pf1 = *(const s16x8*)(Pb + 32);
        O[0] = __builtin_amdgcn_mfma_f32_16x16x32_bf16(Pf0, Gc[0], O[0], 0, 0, 0);
        O[1] = __builtin_amdgcn_mfma_f32_16x16x32_bf16(Pf0, Gc[1], O[1], 0, 0, 0);
        O[0] = __builtin_amdgcn_mfma_f32_16x16x32_bf16(Pf1, Gc[2], O[0], 0, 0, 0);
        O[1] = __builtin_amdgcn_mfma_f32_16x16x32_bf16(Pf1, Gc[3], O[1], 0, 0, 0);
    }

    // l: butterfly-sum partials over the 16 s-group lanes (same q map as O)
    f32x4 linv;
#pragma unroll
    for (int r = 0; r < 4; ++r) {
        float v = l4[r];
        v += __shfl_xor(v, 1);
        v += __shfl_xor(v, 2);
        v += __shfl_xor(v, 4);
        v += __shfl_xor(v, 8);
        linv[r] = 1.f / v;
    }

    __syncthreads();                          // all waves done with P area
    float* otile = (float*)smem;              // [32 c][68 q-stride]
#pragma unroll
    for (int cs = 0; cs < 2; ++cs) {
        f32x4 v;
#pragma unroll
        for (int r = 0; r < 4; ++r) v[r] = O[cs][r] * linv[r];
        *(f32x4*)(otile + (cs * 16 + lr) * 68 + wave * 16 + quad * 4) = v;
    }
    __syncthreads();

    // Wo epilogue + residual
    const int qq = tid & 63;
    const int quarter = __builtin_amdgcn_readfirstlane(tid >> 6);
    float acc[16];
#pragma unroll
    for (int j = 0; j < 16; ++j) acc[j] = 0.f;
    for (int c = 0; c < 32; ++c) {
        const float ov = otile[c * 68 + qq];
#pragma unroll
        for (int j = 0; j < 16; ++j)
            acc[j] += Wo[(quarter * 16 + j) * 32 + c] * ov;
    }
    const float gam = gamma_p[0];
#pragma unroll
    for (int j = 0; j < 16; ++j) {
        const size_t a = ((size_t)b * NC + quarter * 16 + j) * HWs + q0 + qq;
        out[a] = gam * acc[j] + x[a];
    }
}

extern "C" void kernel_launch(void* const* d_in, const int* in_sizes, int n_in,
                              void* d_out, int out_size, void* d_ws, size_t ws_size,
                              hipStream_t stream) {
    const float* x     = (const float*)d_in[0];
    const float* Wt    = (const float*)d_in[1];
    const float* Wp    = (const float*)d_in[2];
    const float* Wg    = (const float*)d_in[3];
    const float* Wo    = (const float*)d_in[4];
    const float* gamma = (const float*)d_in[5];
    float* out = (float*)d_out;
    unsigned short* ws = (unsigned short*)d_ws;

    k_proj<<<256, 256, 0, stream>>>(x, Wt, Wp, Wg, ws);
    k_attn<<<1024, 256, 0, stream>>>(x, Wo, gamma, ws, out);
}